// Round 4
// baseline (496.903 us; speedup 1.0000x reference)
//
#include <hip/hip_runtime.h>
#include <hip/hip_bf16.h>

#define S_IMG 1024
#define NBLK_SCATTER 2048

// Scatter: corners privatized in registers (the only truly hot addresses,
// ~101k hits each); edge + interior pixels go straight to global atomicMax
// (worst edge address ~500 hits -> ~1.6us serialized, parallel across pixels).
__global__ __launch_bounds__(256) void gr_scatter(const float4* __restrict__ pos4,
                                                  int* __restrict__ winner,
                                                  int nquad) {
    __shared__ int csh[4];
    if (threadIdx.x < 4) csh[threadIdx.x] = -1;
    __syncthreads();

    int c00 = -1, c10 = -1, c01 = -1, c11 = -1;   // (x,y): 00,1023-0,0-1023,1023-1023
    const int stride = gridDim.x * 256;
    for (int q = blockIdx.x * 256 + threadIdx.x; q < nquad; q += stride) {
        // 4 gaussians = 12 floats = 3 aligned float4 loads
        float4 a = pos4[3 * q + 0];
        float4 b = pos4[3 * q + 1];
        float4 c = pos4[3 * q + 2];
        float xs[4] = {a.x, a.w, b.z, c.y};
        float ys[4] = {a.y, b.x, b.w, c.z};
        int base = 4 * q;
        #pragma unroll
        for (int j = 0; j < 4; ++j) {
            // JAX: clip(((p+1)*512).astype(int32),0,1023); astype truncs to 0 == C cast
            int x = (int)((xs[j] + 1.0f) * 512.0f);
            int y = (int)((ys[j] + 1.0f) * 512.0f);
            x = min(max(x, 0), S_IMG - 1);
            y = min(max(y, 0), S_IMG - 1);
            int i = base + j;
            bool xe = (x == 0) | (x == S_IMG - 1);
            bool ye = (y == 0) | (y == S_IMG - 1);
            if (xe & ye) {
                // i is monotone increasing per thread -> plain assign == max
                if (x == 0) { if (y == 0) c00 = i; else c01 = i; }
                else        { if (y == 0) c10 = i; else c11 = i; }
            } else {
                atomicMax(&winner[(y << 10) + x], i);
            }
        }
    }
    // wave-level butterfly reduce of the 4 corner maxes
    #pragma unroll
    for (int off = 32; off; off >>= 1) {
        c00 = max(c00, __shfl_xor(c00, off));
        c10 = max(c10, __shfl_xor(c10, off));
        c01 = max(c01, __shfl_xor(c01, off));
        c11 = max(c11, __shfl_xor(c11, off));
    }
    if ((threadIdx.x & 63) == 0) {
        if (c00 >= 0) atomicMax(&csh[0], c00);
        if (c10 >= 0) atomicMax(&csh[1], c10);
        if (c01 >= 0) atomicMax(&csh[2], c01);
        if (c11 >= 0) atomicMax(&csh[3], c11);
    }
    __syncthreads();
    if (threadIdx.x < 4) {
        int v = csh[threadIdx.x];
        if (v >= 0) {
            const int addr[4] = {0, S_IMG - 1, (S_IMG - 1) * S_IMG, S_IMG * S_IMG - 1};
            atomicMax(&winner[addr[threadIdx.x]], v);
        }
    }
}

// Resolve: 4 pixels/thread, int4 winner load, 4 independent gather chains,
// float4 planar stores.
__global__ __launch_bounds__(256) void gr_resolve(const int* __restrict__ winner,
                                                  const float* __restrict__ colors,
                                                  const float* __restrict__ opacities,
                                                  float* __restrict__ out) {
    const int SS = S_IMG * S_IMG;
    int t = blockIdx.x * 256 + threadIdx.x;     // quad-pixel id in [0, SS/4)
    if (t >= SS / 4) return;
    int4 w4 = *(const int4*)(winner + 4 * t);
    int ws[4] = {w4.x, w4.y, w4.z, w4.w};
    float r[4], g[4], b[4], al[4];
    #pragma unroll
    for (int j = 0; j < 4; ++j) {
        int w = ws[j];
        float rr = 0.f, gg = 0.f, bb = 0.f, aa = 0.f;
        if (w >= 0) {
            float o = opacities[w];
            rr = colors[3 * w + 0] * o;
            gg = colors[3 * w + 1] * o;
            bb = colors[3 * w + 2] * o;
            aa = o;
        }
        r[j] = rr; g[j] = gg; b[j] = bb; al[j] = aa;
    }
    *(float4*)(out + 0 * SS + 4 * t) = make_float4(r[0], r[1], r[2], r[3]);
    *(float4*)(out + 1 * SS + 4 * t) = make_float4(g[0], g[1], g[2], g[3]);
    *(float4*)(out + 2 * SS + 4 * t) = make_float4(b[0], b[1], b[2], b[3]);
    *(float4*)(out + 3 * SS + 4 * t) = make_float4(al[0], al[1], al[2], al[3]);
}

extern "C" void kernel_launch(void* const* d_in, const int* in_sizes, int n_in,
                              void* d_out, int out_size, void* d_ws, size_t ws_size,
                              hipStream_t stream) {
    const float* positions = (const float*)d_in[0];   // (N,3)
    const float* colors    = (const float*)d_in[1];   // (N,3)
    const float* opacities = (const float*)d_in[2];   // (N,)
    float* out = (float*)d_out;                       // (1,4,S,S) float32

    const int n  = in_sizes[0] / 3;                   // 4,000,000 (divisible by 4)
    const int SS = S_IMG * S_IMG;
    int* winner = (int*)d_ws;                         // SS ints (4 MB)

    hipMemsetAsync(winner, 0xFF, (size_t)SS * sizeof(int), stream);

    gr_scatter<<<NBLK_SCATTER, 256, 0, stream>>>((const float4*)positions, winner, n / 4);
    gr_resolve<<<(SS / 4 + 255) / 256, 256, 0, stream>>>(winner, colors, opacities, out);
}

// Round 5
// 227.026 us; speedup vs baseline: 2.1888x; 2.1888x over previous
//
#include <hip/hip_runtime.h>
#include <hip/hip_bf16.h>

#define S_IMG 1024
#define BORDER_SLOTS 4096   // 1024 top | 1024 bottom | 1022 left | 1022 right (+pad)
#define NB 512              // scatter blocks == border scratch slabs
#define NCHUNK 16           // parallel chunks in border reduce

// Scatter, three-way routed by contention level:
//   corners (~101k hits each)  -> per-thread registers, reduced at block end
//   edges   (~500 hits max)    -> per-block LDS privatization (slot hits ~1-2
//                                 per block now), slab-flushed
//   interior (~2 hits avg)     -> direct global atomicMax
// Direct global atomics on edges are NOT ok (R4: 354us) — border rows pack 16
// hot pixels per 64B line -> ~8k atomics/line serialize at L2 and stall waves
// via in-order vmcnt retire.
__global__ __launch_bounds__(1024) void gr_scatter(const float4* __restrict__ pos4,
                                                   int* __restrict__ winner,
                                                   int* __restrict__ border_scratch,
                                                   int nquad) {
    __shared__ int lds_border[BORDER_SLOTS];
    #pragma unroll
    for (int t = threadIdx.x; t < BORDER_SLOTS; t += 1024) lds_border[t] = -1;
    __syncthreads();

    int c00 = -1, c10 = -1, c01 = -1, c11 = -1;  // corners (x,y)=(0,0),(1023,0),(0,1023),(1023,1023)
    const int stride = gridDim.x * 1024;
    for (int q = blockIdx.x * 1024 + threadIdx.x; q < nquad; q += stride) {
        float4 a = pos4[3 * q + 0];
        float4 b = pos4[3 * q + 1];
        float4 c = pos4[3 * q + 2];
        float xs[4] = {a.x, a.w, b.z, c.y};
        float ys[4] = {a.y, b.x, b.w, c.z};
        int base = 4 * q;
        #pragma unroll
        for (int j = 0; j < 4; ++j) {
            // JAX: clip(((p+1)*512).astype(int32),0,1023); astype trunc == C cast
            int x = (int)((xs[j] + 1.0f) * 512.0f);
            int y = (int)((ys[j] + 1.0f) * 512.0f);
            x = min(max(x, 0), S_IMG - 1);
            y = min(max(y, 0), S_IMG - 1);
            int i = base + j;
            bool xe = (x == 0) | (x == S_IMG - 1);
            bool ye = (y == 0) | (y == S_IMG - 1);
            if (xe & ye) {
                // i monotone increasing per thread -> assign == running max
                if (x == 0) { if (y == 0) c00 = i; else c01 = i; }
                else        { if (y == 0) c10 = i; else c11 = i; }
            } else if (xe | ye) {
                int idx;
                if (y == 0)              idx = x;
                else if (y == S_IMG - 1) idx = 1024 + x;
                else if (x == 0)         idx = 2048 + (y - 1);
                else                     idx = 3072 + (y - 1);
                atomicMax(&lds_border[idx], i);
            } else {
                atomicMax(&winner[(y << 10) + x], i);
            }
        }
    }
    // corner reduce: wave butterfly, then 4 LDS slots (reuse pad slots 3070/3071
    // would alias left-edge range? no: 3070,3071 unused by edges -> safe), then
    // 4 global atomics per block (512 per corner address, ~1.6us parallel x4).
    #pragma unroll
    for (int off = 32; off; off >>= 1) {
        c00 = max(c00, __shfl_xor(c00, off));
        c10 = max(c10, __shfl_xor(c10, off));
        c01 = max(c01, __shfl_xor(c01, off));
        c11 = max(c11, __shfl_xor(c11, off));
    }
    __syncthreads();   // edge atomics done before flush; also orders corner slots
    if ((threadIdx.x & 63) == 0) {
        if (c00 >= 0) atomicMax(&lds_border[1024 + 0 - 1024 + 3070], c00); // slot 3070 pad
        // (slot arithmetic kept literal below for clarity)
    }
    // simpler: dedicated shared corner cells
    __shared__ int csh[4];
    if (threadIdx.x < 4) csh[threadIdx.x] = -1;
    __syncthreads();
    if ((threadIdx.x & 63) == 0) {
        if (c00 >= 0) atomicMax(&csh[0], c00);
        if (c10 >= 0) atomicMax(&csh[1], c10);
        if (c01 >= 0) atomicMax(&csh[2], c01);
        if (c11 >= 0) atomicMax(&csh[3], c11);
    }
    __syncthreads();
    if (threadIdx.x < 4) {
        int v = csh[threadIdx.x];
        if (v >= 0) {
            const int addr[4] = {0, S_IMG - 1, (S_IMG - 1) * S_IMG, S_IMG * S_IMG - 1};
            atomicMax(&winner[addr[threadIdx.x]], v);
        }
    }
    // coalesced slab flush (int4)
    int4* dst = (int4*)(border_scratch + (size_t)blockIdx.x * BORDER_SLOTS);
    const int4* src = (const int4*)lds_border;
    for (int t = threadIdx.x; t < BORDER_SLOTS / 4; t += 1024) dst[t] = src[t];
}

// Border reduce: NCHUNK chunks each max-reduce NB/NCHUNK slabs (coalesced
// slab-major reads), then one low-contention global atomicMax per (slot,chunk).
// Corner slots stay -1 in every slab (never written) -> skipped.
__global__ __launch_bounds__(256) void gr_border_reduce(const int* __restrict__ border_scratch,
                                                        int* __restrict__ winner) {
    int p = blockIdx.x * 256 + threadIdx.x;   // slot in [0, 4096)
    int b0 = blockIdx.y * (NB / NCHUNK);
    int m = -1;
    #pragma unroll 4
    for (int b = 0; b < NB / NCHUNK; ++b)
        m = max(m, border_scratch[(size_t)(b0 + b) * BORDER_SLOTS + p]);
    if (m < 0) return;
    int x, y;
    if (p < 1024)      { x = p;        y = 0; }
    else if (p < 2048) { x = p - 1024; y = S_IMG - 1; }
    else if (p < 3072) { int r = p - 2048; if (r > 1021) return; x = 0;         y = r + 1; }
    else               { int r = p - 3072; if (r > 1021) return; x = S_IMG - 1; y = r + 1; }
    atomicMax(&winner[y * S_IMG + x], m);
}

// Resolve: 4 pixels/thread, int4 winner load, 4 independent gather chains,
// float4 planar stores.
__global__ __launch_bounds__(256) void gr_resolve(const int* __restrict__ winner,
                                                  const float* __restrict__ colors,
                                                  const float* __restrict__ opacities,
                                                  float* __restrict__ out) {
    const int SS = S_IMG * S_IMG;
    int t = blockIdx.x * 256 + threadIdx.x;
    if (t >= SS / 4) return;
    int4 w4 = *(const int4*)(winner + 4 * t);
    int ws[4] = {w4.x, w4.y, w4.z, w4.w};
    float r[4], g[4], b[4], al[4];
    #pragma unroll
    for (int j = 0; j < 4; ++j) {
        int w = ws[j];
        float rr = 0.f, gg = 0.f, bb = 0.f, aa = 0.f;
        if (w >= 0) {
            float o = opacities[w];
            rr = colors[3 * w + 0] * o;
            gg = colors[3 * w + 1] * o;
            bb = colors[3 * w + 2] * o;
            aa = o;
        }
        r[j] = rr; g[j] = gg; b[j] = bb; al[j] = aa;
    }
    *(float4*)(out + 0 * SS + 4 * t) = make_float4(r[0], r[1], r[2], r[3]);
    *(float4*)(out + 1 * SS + 4 * t) = make_float4(g[0], g[1], g[2], g[3]);
    *(float4*)(out + 2 * SS + 4 * t) = make_float4(b[0], b[1], b[2], b[3]);
    *(float4*)(out + 3 * SS + 4 * t) = make_float4(al[0], al[1], al[2], al[3]);
}

extern "C" void kernel_launch(void* const* d_in, const int* in_sizes, int n_in,
                              void* d_out, int out_size, void* d_ws, size_t ws_size,
                              hipStream_t stream) {
    const float* positions = (const float*)d_in[0];   // (N,3)
    const float* colors    = (const float*)d_in[1];   // (N,3)
    const float* opacities = (const float*)d_in[2];   // (N,)
    float* out = (float*)d_out;                       // (1,4,S,S) float32

    const int n  = in_sizes[0] / 3;                   // 4,000,000
    const int SS = S_IMG * S_IMG;

    int* winner         = (int*)d_ws;                 // SS ints (4 MB)
    int* border_scratch = winner + SS;                // NB*4096 ints (8 MB)

    hipMemsetAsync(winner, 0xFF, (size_t)SS * sizeof(int), stream);

    gr_scatter<<<NB, 1024, 0, stream>>>((const float4*)positions, winner,
                                        border_scratch, n / 4);

    dim3 grid_br(BORDER_SLOTS / 256, NCHUNK);
    gr_border_reduce<<<grid_br, 256, 0, stream>>>(border_scratch, winner);

    gr_resolve<<<(SS / 4 + 255) / 256, 256, 0, stream>>>(winner, colors, opacities, out);
}